// Round 13
// baseline (473.281 us; speedup 1.0000x reference)
//
#include <hip/hip_runtime.h>
#include <hip/hip_bf16.h>
#include <cstdint>
#include <cstddef>

typedef __attribute__((ext_vector_type(8))) short short8;
typedef __attribute__((ext_vector_type(4))) short short4_;
typedef __attribute__((ext_vector_type(4))) float floatx4;
typedef __attribute__((ext_vector_type(4))) unsigned short ushort4_;

#define MFMA16(a, b, c) __builtin_amdgcn_mfma_f32_16x16x32_bf16((a), (b), (c), 0, 0, 0)

__device__ __forceinline__ unsigned short f2bf(float f) {
  __hip_bfloat16 h = __float2bfloat16(f);
  return *reinterpret_cast<unsigned short*>(&h);
}

__device__ __forceinline__ void gl_lds16(const void* g, void* lds) {
  __builtin_amdgcn_global_load_lds(
      (const __attribute__((address_space(1))) void*)g,
      (__attribute__((address_space(3))) void*)lds, 16, 0, 0);
}

// ---------------------------------------------------------------- fused cast kernel
__global__ void cast5_f32_bf16(const float* __restrict__ x, const float* __restrict__ wq,
                               const float* __restrict__ wk, const float* __restrict__ wv,
                               const float* __restrict__ wo,
                               __hip_bfloat16* __restrict__ xb, __hip_bfloat16* __restrict__ wqb,
                               __hip_bfloat16* __restrict__ wkb, __hip_bfloat16* __restrict__ wvb,
                               __hip_bfloat16* __restrict__ wob) {
  const int bid = blockIdx.x;
  const float* src;
  __hip_bfloat16* dst;
  int base;
  if (bid < 16384)      { src = x;  dst = xb;  base = bid; }
  else if (bid < 20480) { src = wq; dst = wqb; base = bid - 16384; }
  else if (bid < 24576) { src = wk; dst = wkb; base = bid - 20480; }
  else if (bid < 28672) { src = wv; dst = wvb; base = bid - 24576; }
  else                  { src = wo; dst = wob; base = bid - 28672; }
  const int i = base * 1024 + threadIdx.x * 4;
  const float4 v = *reinterpret_cast<const float4*>(src + i);
  ushort4_ o = { f2bf(v.x), f2bf(v.y), f2bf(v.z), f2bf(v.w) };
  *reinterpret_cast<ushort4_*>(dst + i) = o;
}

// ---------------------------------------------------------------- GEMM: 256x256 tile, BK=32
// Phase-split schedule, 4-slot LDS ring, prefetch distance 3, counted vmcnt (never 0 in loop).
// Proven rounds 9-12 (~65 us/dispatch, 0 bank conflicts). UNCHANGED.
template <int MODE>
__global__ __launch_bounds__(512, 2)
void gemm256p(const __hip_bfloat16* __restrict__ Ap, const __hip_bfloat16* __restrict__ Bp,
              const float* __restrict__ bias, void* __restrict__ Cout,
              int M, int N, int K) {
  __shared__ __align__(16) __hip_bfloat16 SA[4][256 * 32];
  __shared__ __align__(16) __hip_bfloat16 SB[4][256 * 32];

  const int tid = threadIdx.x;
  const int wid = tid >> 6, lane = tid & 63;
  const int wr = wid >> 2, wc = wid & 3;
  const int g = lane >> 4, c16 = lane & 15;

  const int nbn = N >> 8;
  const int cpx = gridDim.x >> 3;
  const int swzb = (blockIdx.x & 7) * cpx + (blockIdx.x >> 3);
  const int bm = swzb / nbn, bn = swzb % nbn;

  const int srow = lane >> 2;
  const int slog = (lane & 3) ^ ((lane >> 3) & 3);
  const int swz = c16 * 32 + (g ^ ((c16 >> 1) & 3)) * 8;

  floatx4 acc[8][4] = {};
  short8 afA[4], afB[4], bf[4];

  auto stage_i = [&](int kt, int i) {
    const int kb = kt * 32;
    const int slot = kt & 3;
    const int rbase = i * 128 + wid * 16;
    gl_lds16(Ap + (size_t)(bm * 256 + rbase + srow) * K + kb + slog * 8,
             SA[slot] + rbase * 32);
    gl_lds16(Bp + (size_t)(bn * 256 + rbase + srow) * K + kb + slog * 8,
             SB[slot] + rbase * 32);
  };

  auto readA = [&](int slot, int half, short8* af) {
    const __hip_bfloat16* sa = SA[slot];
#pragma unroll
    for (int m = 0; m < 4; ++m)
      af[m] = *reinterpret_cast<const short8*>(sa + wr * 4096 + (half * 4 + m) * 512 + swz);
  };
  auto readB = [&](int slot) {
    const __hip_bfloat16* sb = SB[slot];
#pragma unroll
    for (int n = 0; n < 4; ++n)
      bf[n] = *reinterpret_cast<const short8*>(sb + wc * 2048 + n * 512 + swz);
  };
  auto mfma16 = [&](short8* af, int mh) {
    __builtin_amdgcn_s_setprio(1);
#pragma unroll
    for (int m = 0; m < 4; ++m)
#pragma unroll
      for (int n = 0; n < 4; ++n)
        acc[mh * 4 + m][n] = MFMA16(af[m], bf[n], acc[mh * 4 + m][n]);
    __builtin_amdgcn_s_setprio(0);
  };

  const int nkt = K >> 5;
  stage_i(0, 0); stage_i(0, 1);
  stage_i(1, 0); stage_i(1, 1);
  stage_i(2, 0); stage_i(2, 1);
  asm volatile("s_waitcnt vmcnt(8)" ::: "memory");   // drain tile 0
  __builtin_amdgcn_s_barrier();

  for (int kt = 0; kt < nkt - 3; ++kt) {
    const int s = kt & 3;
    readA(s, 0, afA);
    readB(s);
    stage_i(kt + 3, 0);
    asm volatile("" ::: "memory");
    __builtin_amdgcn_s_barrier();
    mfma16(afA, 0);
    asm volatile("" ::: "memory");
    __builtin_amdgcn_s_barrier();
    readA(s, 1, afB);
    stage_i(kt + 3, 1);
    asm volatile("s_waitcnt vmcnt(8)" ::: "memory");
    __builtin_amdgcn_s_barrier();
    mfma16(afB, 1);
    asm volatile("" ::: "memory");
    __builtin_amdgcn_s_barrier();
  }
#pragma unroll
  for (int t = 0; t < 3; ++t) {
    const int kt = nkt - 3 + t;
    const int s = kt & 3;
    readA(s, 0, afA);
    readB(s);
    asm volatile("" ::: "memory");
    __builtin_amdgcn_s_barrier();
    mfma16(afA, 0);
    asm volatile("" ::: "memory");
    __builtin_amdgcn_s_barrier();
    readA(s, 1, afB);
    if (t == 0) asm volatile("s_waitcnt vmcnt(4)" ::: "memory");
    else if (t == 1) asm volatile("s_waitcnt vmcnt(0)" ::: "memory");
    __builtin_amdgcn_s_barrier();
    mfma16(afB, 1);
    asm volatile("" ::: "memory");
    __builtin_amdgcn_s_barrier();
  }

#pragma unroll
  for (int n = 0; n < 4; ++n) {
    const int colg = bn * 256 + wc * 64 + n * 16 + c16;
    const float bv = bias[colg];
#pragma unroll
    for (int m = 0; m < 8; ++m) {
      const int rowg = bm * 256 + wr * 128 + m * 16 + g * 4;
      if (MODE == 0) {
        __hip_bfloat16* C = (__hip_bfloat16*)Cout;
#pragma unroll
        for (int j = 0; j < 4; ++j)
          C[(size_t)(rowg + j) * N + colg] = __float2bfloat16(acc[m][n][j] + bv);
      } else if (MODE == 1) {
        __hip_bfloat16* C = (__hip_bfloat16*)Cout;
        const int bb = rowg >> 11, t0 = rowg & 2047;
        ushort4_ pk = { f2bf(acc[m][n][0] + bv), f2bf(acc[m][n][1] + bv),
                        f2bf(acc[m][n][2] + bv), f2bf(acc[m][n][3] + bv) };
        *reinterpret_cast<ushort4_*>(C + ((size_t)bb * 2048 + colg) * 2048 + t0) = pk;
      } else {
        float* C = (float*)Cout;
#pragma unroll
        for (int j = 0; j < 4; ++j)
          C[(size_t)(rowg + j) * N + colg] = acc[m][n][j] + bv;
      }
    }
  }
}

// ---------------------------------------------------------------- flash attention v9 (causal)
// 512 threads = 8 waves x 16 q-rows (QBLK=128). Halved per-wave state
// (acc[8]=32 AGPR, qf[4]=16) -> VGPR ~100 -> LB(512,4) -> 4 waves/SIMD, 2 blocks/CU.
// Single-buffer K/V (r11 schedule), XOR-swizzled LDS, swapped-operand softmax.
__global__ __launch_bounds__(512, 4)
void attn_fwd9(const __hip_bfloat16* __restrict__ Q, const __hip_bfloat16* __restrict__ K,
               const __hip_bfloat16* __restrict__ Vt, __hip_bfloat16* __restrict__ ctx) {
  constexpr int T = 2048, C = 2048, D = 128;
  __shared__ __align__(16) __hip_bfloat16 Ks[64 * 128];    // 16 KB, slot^(row&7)
  __shared__ __align__(16) __hip_bfloat16 Vs[128 * 64];    // 16 KB, slot^(row&7)
  __shared__ __align__(16) __hip_bfloat16 Pl[8][16 * 64];  // 16 KB, slot^c16, per-wave
  // total 49152 B -> 2 blocks/CU

  const int tid = threadIdx.x;
  const int w = tid >> 6, lane = tid & 63;
  const int g = lane >> 4, c16 = lane & 15;

  // pair-balanced causal mapping: consecutive pair (15-t, t) sums to 15;
  // each head keeps all 16 q-blocks on one XCD.
  const int bid = blockIdx.x;
  const int x = bid & 7;
  const int i = bid >> 3;               // 0..127 within XCD
  const int bh = x * 8 + ((i >> 1) & 7);
  const int t = i >> 4;                 // 0..7
  const int qb = (i & 1) ? t : 15 - t;
  const int b = bh >> 4, h = bh & 15;
  const int wq = qb * 128 + w * 16;     // wave's 16 q-rows

  const __hip_bfloat16* Qh = Q + (size_t)b * T * C + h * D;
  const __hip_bfloat16* Kh = K + (size_t)b * T * C + h * D;
  const __hip_bfloat16* Vh = Vt + (size_t)bh * D * T;

  short8 qf[4];
#pragma unroll
  for (int kk = 0; kk < 4; ++kk)
    qf[kk] = *reinterpret_cast<const short8*>(Qh + (size_t)(wq + c16) * C + kk * 32 + g * 8);

  floatx4 acc[8] = {};                  // O^T: row d_local = g*4+j, col q = c16
  float mrow = -INFINITY, lrow = 0.f;

  const float scale = 0.08838834764831845f;   // 1/sqrt(128)
  // staging (512 threads, 2 x 16B slots each)
  const int kR = tid >> 4;                    // 0..31
  const int kS = (tid & 15) ^ (kR & 7);       // XOR'd slot (row&7 invariant to +32)
  const int kC = (tid & 15) * 8;
  const int vR = tid >> 3;                    // 0..63
  const int vS = (tid & 7) ^ (vR & 7);        // (row&7 invariant to +64)
  const int vC = (tid & 7) * 8;

  short8 kr[2], vr[2];
  auto gloadK = [&](int kb) {
#pragma unroll
    for (int p = 0; p < 2; ++p)
      kr[p] = *reinterpret_cast<const short8*>(Kh + (size_t)(kb + p * 32 + kR) * C + kC);
  };
  auto gloadV = [&](int kb) {
#pragma unroll
    for (int p = 0; p < 2; ++p)
      vr[p] = *reinterpret_cast<const short8*>(Vh + (size_t)(p * 64 + vR) * T + kb + vC);
  };

  __hip_bfloat16* Pq = Pl[w];
  const int nkt = qb * 2 + 2;
  gloadK(0);
  gloadV(0);

  for (int kt = 0; kt < nkt; ++kt) {
    const int kb = kt * 64;
    __syncthreads();                    // prior tile consumed; drains prefetch regs
#pragma unroll
    for (int p = 0; p < 2; ++p)
      *reinterpret_cast<short8*>(&Ks[(p * 32 + kR) * 128 + kS * 8]) = kr[p];
#pragma unroll
    for (int p = 0; p < 2; ++p)
      *reinterpret_cast<short8*>(&Vs[(p * 64 + vR) * 64 + vS * 8]) = vr[p];
    __syncthreads();                    // staged tile visible

    const bool hasnext = (kt + 1 < nkt);
    const bool part = (kb <= wq + 15);  // wave-uniform participation
    if (hasnext) gloadK(kb + 64);

    short8 pb[2];
    if (part) {
      const bool needmask = (kb + 63 > wq);
      floatx4 s[4] = {};
      __builtin_amdgcn_s_setprio(1);
#pragma unroll
      for (int n = 0; n < 4; ++n)
#pragma unroll
        for (int kk = 0; kk < 4; ++kk) {
          short8 kf = *reinterpret_cast<const short8*>(
              &Ks[(n * 16 + c16) * 128 + (((kk * 4 + g) ^ (c16 & 7)) * 8)]);
          s[n] = MFMA16(kf, qf[kk], s[n]);
        }
      __builtin_amdgcn_s_setprio(0);
      // scale + mask + lane-local row max (row q = wq + c16)
      const int q = wq + c16;
      float vm = -INFINITY;
#pragma unroll
      for (int n = 0; n < 4; ++n)
#pragma unroll
        for (int j = 0; j < 4; ++j) {
          float a = s[n][j] * scale;
          if (needmask && (kb + n * 16 + g * 4 + j > q)) a = -INFINITY;
          s[n][j] = a;
          vm = fmaxf(vm, a);
        }
      vm = fmaxf(vm, __shfl_xor(vm, 16));
      vm = fmaxf(vm, __shfl_xor(vm, 32));
      // T13 defer-max
      const bool nore = __all(vm - mrow <= 8.0f);
      const float mn = nore ? mrow : fmaxf(mrow, vm);
      float rs = 0.f;
#pragma unroll
      for (int n = 0; n < 4; ++n) {
        float p0 = __expf(s[n][0] - mn), p1 = __expf(s[n][1] - mn);
        float p2 = __expf(s[n][2] - mn), p3 = __expf(s[n][3] - mn);
        rs += (p0 + p1) + (p2 + p3);
        ushort4_ pk = { f2bf(p0), f2bf(p1), f2bf(p2), f2bf(p3) };
        *reinterpret_cast<ushort4_*>(&Pq[c16 * 64 + (((4 * n + g) ^ c16) * 4)]) = pk;
      }
      rs += __shfl_xor(rs, 16);
      rs += __shfl_xor(rs, 32);
      if (nore) {
        lrow += rs;
      } else {
        const float sc = __expf(mrow - mn);
        lrow = lrow * sc + rs;
        mrow = mn;
#pragma unroll
        for (int dt = 0; dt < 8; ++dt)
#pragma unroll
          for (int j = 0; j < 4; ++j) acc[dt][j] *= sc;
      }
      // read P fragments (DS in-order per wave: writes above retire first)
#pragma unroll
      for (int ks = 0; ks < 2; ++ks) {
        short4_ lo2 = *reinterpret_cast<const short4_*>(&Pq[c16 * 64 + (((8 * ks + 2 * g) ^ c16) * 4)]);
        short4_ hi2 = *reinterpret_cast<const short4_*>(&Pq[c16 * 64 + (((8 * ks + 2 * g + 1) ^ c16) * 4)]);
        short8 r;
        r[0] = lo2[0]; r[1] = lo2[1]; r[2] = lo2[2]; r[3] = lo2[3];
        r[4] = hi2[0]; r[5] = hi2[1]; r[6] = hi2[2]; r[7] = hi2[3];
        pb[ks] = r;
      }
    }
    if (hasnext) gloadV(kb + 64);
    if (part) {
      __builtin_amdgcn_s_setprio(1);
#pragma unroll
      for (int dt = 0; dt < 8; ++dt)
#pragma unroll
        for (int ks = 0; ks < 2; ++ks) {
          const int pslot = ((ks * 4 + g) ^ (c16 & 7)) * 8;
          short8 vf = *reinterpret_cast<const short8*>(&Vs[(dt * 16 + c16) * 64 + pslot]);
          acc[dt] = MFMA16(vf, pb[ks], acc[dt]);
        }
      __builtin_amdgcn_s_setprio(0);
    }
  }

  // epilogue: O^T -> ctx[q][d]; lane writes 4 contiguous d (8B) per dt
  const float inv = 1.0f / lrow;
  const size_t row = (size_t)b * T + wq + c16;
#pragma unroll
  for (int dt = 0; dt < 8; ++dt) {
    ushort4_ o = { f2bf(acc[dt][0] * inv), f2bf(acc[dt][1] * inv),
                   f2bf(acc[dt][2] * inv), f2bf(acc[dt][3] * inv) };
    *reinterpret_cast<ushort4_*>(ctx + row * C + h * D + dt * 16 + g * 4) = o;
  }
}

// ---------------------------------------------------------------- launch
extern "C" void kernel_launch(void* const* d_in, const int* in_sizes, int n_in,
                              void* d_out, int out_size, void* d_ws, size_t ws_size,
                              hipStream_t stream) {
  const float* x  = (const float*)d_in[0];
  const float* Wq = (const float*)d_in[1];
  const float* bq = (const float*)d_in[2];
  const float* Wk = (const float*)d_in[3];
  const float* bk = (const float*)d_in[4];
  const float* Wv = (const float*)d_in[5];
  const float* bv = (const float*)d_in[6];
  const float* Wo = (const float*)d_in[7];
  const float* bo = (const float*)d_in[8];

  const int M = 8192, N = 2048, K = 2048;
  const size_t MB = 1u << 20;
  char* ws = (char*)d_ws;
  __hip_bfloat16* xb  = (__hip_bfloat16*)(ws);
  __hip_bfloat16* wqb = (__hip_bfloat16*)(ws + 32 * MB);
  __hip_bfloat16* wkb = (__hip_bfloat16*)(ws + 40 * MB);
  __hip_bfloat16* wvb = (__hip_bfloat16*)(ws + 48 * MB);
  __hip_bfloat16* wob = (__hip_bfloat16*)(ws + 56 * MB);
  __hip_bfloat16* Qb  = (__hip_bfloat16*)(ws + 64 * MB);
  __hip_bfloat16* Kb  = (__hip_bfloat16*)(ws + 96 * MB);
  __hip_bfloat16* Vtb = (__hip_bfloat16*)(ws + 128 * MB);
  if (ws_size < 160 * MB) return;

  cast5_f32_bf16<<<32768, 256, 0, stream>>>(x, Wq, Wk, Wv, Wo, xb, wqb, wkb, wvb, wob);

  const dim3 gg((M / 256) * (N / 256));
  gemm256p<0><<<gg, 512, 0, stream>>>(xb, wqb, bq, Qb, M, N, K);
  gemm256p<0><<<gg, 512, 0, stream>>>(xb, wkb, bk, Kb, M, N, K);
  gemm256p<1><<<gg, 512, 0, stream>>>(xb, wvb, bv, Vtb, M, N, K);

  attn_fwd9<<<64 * 16, 512, 0, stream>>>(Qb, Kb, Vtb, xb);

  gemm256p<2><<<gg, 512, 0, stream>>>(xb, wob, bo, d_out, M, N, K);
}